// Round 2
// baseline (342.779 us; speedup 1.0000x reference)
//
#include <hip/hip_runtime.h>

#define CIN   256
#define COUT  256
#define HH    56
#define WW    56
#define BATCH 32
#define KTOT  2304           // CIN * 9, ordered (kh,kw,ci)
#define HP    58
#define WP    58
#define NPIX  (BATCH*HH*WW)  // 100352
#define HWSZ  (HH*WW)        // 3136
#define KT    36             // K-tiles of 64

typedef __bf16 bf16x8 __attribute__((ext_vector_type(8)));
typedef float  f32x4  __attribute__((ext_vector_type(4)));

#define AS1 __attribute__((address_space(1)))
#define AS3 __attribute__((address_space(3)))

__device__ __forceinline__ unsigned short f2bf(float f) {
  union { float f; unsigned int u; } v; v.f = f;
  unsigned int u = v.u;
  u += 0x7fffu + ((u >> 16) & 1u);   // round-to-nearest-even
  return (unsigned short)(u >> 16);
}

__device__ __forceinline__ void async16(const void* g, void* l) {
  __builtin_amdgcn_global_load_lds((const AS1 unsigned int*)g,
                                   (AS3 unsigned int*)l, 16, 0, 0);
}

// ---- kernel 1: ternary-quantize weights, reorder OIHW -> [co][kh][kw][ci] bf16
__global__ __launch_bounds__(256) void quant_w(const float* __restrict__ w,
                                               unsigned short* __restrict__ wr) {
  int tid = blockIdx.x * 256 + threadIdx.x;
  if (tid >= COUT * KTOT) return;
  int co  = tid / KTOT;
  int rem = tid - co * KTOT;
  int tap = rem >> 8;          // kh*3+kw
  int ci  = rem & 255;
  int kh  = tap / 3;
  int kw  = tap - kh * 3;
  float v = w[((co * CIN + ci) * 3 + kh) * 3 + kw];
  float q = (fabsf(v) > 0.05f) ? ((v > 0.f) ? 1.f : -1.f) : 0.f;
  wr[tid] = f2bf(q);           // -1/0/+1 exact in bf16
}

// ---- kernel 2: x NCHW fp32 -> zero-padded NHWC bf16  Xp[n][hp][wp][ci]
__global__ __launch_bounds__(256) void pad_nhwc(const float* __restrict__ x,
                                                unsigned short* __restrict__ xp) {
  const int nhp = blockIdx.x;            // n*58 + hp
  const int n   = nhp / HP;
  const int hp  = nhp - n * HP;
  const int ci0 = blockIdx.y * 64;
  const int t   = threadIdx.x;
  const size_t obase = (size_t)nhp * (WP * 256);

  __shared__ __align__(16) float tile[64 * 56];
  const bool hborder = (hp == 0) || (hp == HP - 1);

  if (!hborder) {
    const int h = hp - 1;
    #pragma unroll
    for (int it = 0; it < 4; ++it) {
      int linear = it * 256 + t;
      if (linear < 896) {
        int cil = linear / 14;
        int w4  = linear - cil * 14;
        *(float4*)&tile[cil * 56 + w4 * 4] =
            *(const float4*)&x[(((size_t)(n * CIN + ci0 + cil)) * HH + h) * WW + w4 * 4];
      }
    }
  }
  __syncthreads();

  #pragma unroll
  for (int it = 0; it < 2; ++it) {               // 58*8 = 464 16B-chunks
    int linear = it * 256 + t;
    if (linear < 464) {
      int wp = linear >> 3;
      int g  = linear & 7;                       // ci group of 8
      unsigned int pk[4] = {0u, 0u, 0u, 0u};
      if (!hborder && wp != 0 && wp != WP - 1) {
        #pragma unroll
        for (int j = 0; j < 4; ++j) {
          unsigned int lo = f2bf(tile[(g * 8 + 2 * j) * 56 + (wp - 1)]);
          unsigned int hi = f2bf(tile[(g * 8 + 2 * j + 1) * 56 + (wp - 1)]);
          pk[j] = lo | (hi << 16);
        }
      }
      uint4 v; v.x = pk[0]; v.y = pk[1]; v.z = pk[2]; v.w = pk[3];
      *(uint4*)(xp + obase + (size_t)wp * 256 + ci0 + g * 8) = v;
    }
  }
}

// ---- kernel 3: implicit GEMM, 256x256 tile, BK=64, 8 waves (2Mx4N),
// 8-phase counted-vmcnt schedule (T3+T4) + chunk-XOR LDS swizzle (T2) +
// setprio (T5) + bijective XCD swizzle (T1).
//
// LDS (128 KiB dynamic):
//   A[buf][khalf][256 co][32 k]  regions of 16 KB at ((b*2+kh)*16384)
//   B[buf][khalf][256 px][32 k]  at 65536 + ((b*2+kh)*16384)
// Swizzle: 16B-chunk c_phys = c_log ^ (row&3); staging keeps LDS linear and
// pre-swizzles the GLOBAL source (rule #21); ds_read applies same XOR.
//
// Pipeline (per tile kk, buffer b=kk&1; phases p1..p4 = (kh,mh)):
//   p1 issue A_kh1(kk+1)->b^1        | p2 issue B_kh1(kk+1)->b^1, vmcnt(8)
//   p3 issue A_kh0(kk+2)->b          | p4 issue B_kh0(kk+2)->b,   vmcnt(8)
// Waits sit BEFORE the trailing barrier => cross-wave safe; every overwrite
// issue is >=1 barrier after the region's last read. Never vmcnt(0) until the
// peeled final tile (vmcnt 4 then 0).

__device__ __forceinline__ int xko_of(int kk) {
  int tap = kk >> 2;               // 0..8
  int k3  = tap / 3;
  int w3  = tap - k3 * 3;
  return (k3 * WP + w3) * 256 + ((kk & 3) << 6);
}

#define NOWAIT (void)0
#define VM8 asm volatile("s_waitcnt vmcnt(8)" ::: "memory")
#define VM4 asm volatile("s_waitcnt vmcnt(4)" ::: "memory")
#define VM0 asm volatile("s_waitcnt vmcnt(0)" ::: "memory")

#define STAGE_A(b_, kh_, kkq_) do {                                           \
  const size_t ko_ = (size_t)(kkq_) * 64 + (kh_) * 32;                        \
  char* d_ = smem + (((b_) * 2 + (kh_)) * 16384) + t * 16;                    \
  async16(Wr + aOff0 + ko_, d_);                                              \
  async16(Wr + aOff1 + ko_, d_ + 8192);                                       \
} while (0)

#define STAGE_B(b_, kh_, xko_) do {                                           \
  const size_t ko_ = (size_t)(xko_) + (kh_) * 32;                             \
  char* d_ = smem + 65536 + (((b_) * 2 + (kh_)) * 16384) + t * 16;            \
  async16(Xp + bOff0 + ko_, d_);                                              \
  async16(Xp + bOff1 + ko_, d_ + 8192);                                       \
} while (0)

#define PHASE(b_, kh_, mh_, WAITE, ...) do {                                  \
  const int abase_ = ((b_) * 2 + (kh_)) * 16384;                              \
  const int bbase_ = 65536 + ((b_) * 2 + (kh_)) * 16384;                      \
  bf16x8 af_[4];                                                              \
  _Pragma("unroll")                                                           \
  for (int mt = 0; mt < 4; ++mt)                                              \
    af_[mt] = *(const bf16x8*)(smem + abase_ + rdA + (mh_) * 4096 + mt * 1024);\
  if ((mh_) == 0) {                                                           \
    _Pragma("unroll")                                                         \
    for (int nt = 0; nt < 4; ++nt)                                            \
      bfr[nt] = *(const bf16x8*)(smem + bbase_ + rdB + nt * 1024);            \
  }                                                                           \
  __VA_ARGS__;                                                                \
  __builtin_amdgcn_s_barrier();                                               \
  asm volatile("s_waitcnt lgkmcnt(0)" ::: "memory");                          \
  __builtin_amdgcn_sched_barrier(0);                                          \
  __builtin_amdgcn_s_setprio(1);                                              \
  _Pragma("unroll")                                                           \
  for (int mt = 0; mt < 4; ++mt)                                              \
    _Pragma("unroll")                                                         \
    for (int nt = 0; nt < 4; ++nt)                                            \
      acc[(mh_) * 4 + mt][nt] = __builtin_amdgcn_mfma_f32_16x16x32_bf16(      \
          af_[mt], bfr[nt], acc[(mh_) * 4 + mt][nt], 0, 0, 0);                \
  __builtin_amdgcn_s_setprio(0);                                              \
  WAITE;                                                                      \
  __builtin_amdgcn_s_barrier();                                               \
} while (0)

#define TILE_FULL(b_, kk_) do {                                               \
  const int kkn1_ = (kk_) + 1, kkn2_ = (kk_) + 2;                             \
  const int xko1_ = xko_of(kkn1_), xko2_ = xko_of(kkn2_);                     \
  PHASE(b_, 0, 0, NOWAIT, STAGE_A((b_) ^ 1, 1, kkn1_));                       \
  PHASE(b_, 0, 1, VM8,    STAGE_B((b_) ^ 1, 1, xko1_));                       \
  PHASE(b_, 1, 0, NOWAIT, STAGE_A((b_), 0, kkn2_));                           \
  PHASE(b_, 1, 1, VM8,    STAGE_B((b_), 0, xko2_));                           \
} while (0)

__global__ __launch_bounds__(512, 2) void conv_gemm(
    const unsigned short* __restrict__ Wr,
    const unsigned short* __restrict__ Xp,
    const float* __restrict__ bias,
    float* __restrict__ out) {
  extern __shared__ char smem[];   // 131072 B

  const int t    = threadIdx.x;
  const int lane = t & 63;
  const int wv   = t >> 6;        // 0..7
  const int wm   = wv >> 2;       // 0..1  (co half)
  const int wn   = wv & 3;        // 0..3  (pixel quarter)
  const int l15  = lane & 15;
  const int quad = lane >> 4;

  // T1: bijective XCD swizzle over 392 = 8 * 49 blocks
  const int bid = blockIdx.x;
  const int pb  = (bid & 7) * 49 + (bid >> 3);
  const int p0  = pb * 256;

  // staging invariants: thread t stages row srow (+128 for sweep 1),
  // physical 16B-chunk t&3, logical chunk schk = (t&3) ^ (row&3)  [T2 inverse]
  const int srow = t >> 2;                       // 0..127
  const int schk = (t & 3) ^ (srow & 3);
  const size_t aOff0 = (size_t)srow * KTOT + schk * 8;
  const size_t aOff1 = aOff0 + (size_t)128 * KTOT;

  const int pA = p0 + srow;
  const int pB = pA + 128;
  const int nA = pA / HWSZ;  const int hwA = pA - nA * HWSZ;
  const int hA = hwA / WW;   const int wA  = hwA - hA * WW;
  const int nB = pB / HWSZ;  const int hwB = pB - nB * HWSZ;
  const int hB = hwB / WW;   const int wB  = hwB - hB * WW;
  const size_t bOff0 = ((size_t)((nA * HP + hA) * WP + wA)) * 256 + schk * 8;
  const size_t bOff1 = ((size_t)((nB * HP + hB) * WP + wB)) * 256 + schk * 8;

  // fragment-read invariants (T2 read-side XOR: chunk = quad ^ (row&3), row&3 = l15&3)
  const int rchk = ((quad ^ (l15 & 3)) * 16);
  const int rdA  = (wm * 128 + l15) * 64 + rchk;   // + mh*4096 + mt*1024
  const int rdB  = (wn * 64 + l15) * 64 + rchk;    // + nt*1024

  f32x4 acc[8][4];
  #pragma unroll
  for (int i = 0; i < 8; ++i)
    #pragma unroll
    for (int j = 0; j < 4; ++j)
      acc[i][j] = (f32x4){0.f, 0.f, 0.f, 0.f};
  bf16x8 bfr[4];

  // ---- prologue: issue (oldest->newest) A0(0) B0(0) A1(0) B1(0) A0(1) B0(1)
  STAGE_A(0, 0, 0);
  STAGE_B(0, 0, xko_of(0));
  STAGE_A(0, 1, 0);
  STAGE_B(0, 1, xko_of(0));
  STAGE_A(1, 0, 1);
  STAGE_B(1, 0, xko_of(1));
  VM8;                               // kh0(0) regions landed (8 still in flight)
  __builtin_amdgcn_s_barrier();

  // ---- main: tiles 0..33, uniform schedule
  #pragma unroll 1
  for (int kk = 0; kk < 34; kk += 2) {
    TILE_FULL(0, kk);
    TILE_FULL(1, kk + 1);
  }
  // ---- tile 34 (b=0): only kh1(35) issues remain; drain tapers 8 -> 4
  {
    const int xko35 = xko_of(35);
    PHASE(0, 0, 0, NOWAIT, STAGE_A(1, 1, 35));
    PHASE(0, 0, 1, VM8,    STAGE_B(1, 1, xko35));
    PHASE(0, 1, 0, NOWAIT, NOWAIT);
    PHASE(0, 1, 1, VM4,    NOWAIT);
  }
  // ---- tile 35 (b=1): final drain 0
  {
    PHASE(1, 0, 0, NOWAIT, NOWAIT);
    PHASE(1, 0, 1, VM0,    NOWAIT);
    PHASE(1, 1, 0, NOWAIT, NOWAIT);
    PHASE(1, 1, 1, NOWAIT, NOWAIT);
  }

  // ---- epilogue: C/D layout col = lane&15 (pixel), row = quad*4+reg (co)
  float bv[8][4];
  #pragma unroll
  for (int m = 0; m < 8; ++m)
    #pragma unroll
    for (int r = 0; r < 4; ++r)
      bv[m][r] = bias[wm * 128 + m * 16 + quad * 4 + r];

  #pragma unroll
  for (int nt = 0; nt < 4; ++nt) {
    const int p  = p0 + wn * 64 + nt * 16 + l15;
    const int np = p / HWSZ;
    const int hw = p - np * HWSZ;
    const size_t obase = (size_t)np * (COUT * HWSZ) + hw;
    #pragma unroll
    for (int m = 0; m < 8; ++m) {
      const int co = wm * 128 + m * 16 + quad * 4;
      #pragma unroll
      for (int r = 0; r < 4; ++r)
        out[obase + (size_t)(co + r) * HWSZ] = acc[m][nt][r] + bv[m][r];
    }
  }
}

extern "C" void kernel_launch(void* const* d_in, const int* in_sizes, int n_in,
                              void* d_out, int out_size, void* d_ws, size_t ws_size,
                              hipStream_t stream) {
  const float* x    = (const float*)d_in[0];
  const float* w    = (const float*)d_in[1];
  const float* bias = (const float*)d_in[2];
  float* out        = (float*)d_out;

  // workspace layout: Xp (padded NHWC bf16) then Wr (reordered ternary bf16)
  unsigned short* xp = (unsigned short*)d_ws;                       // 55,115,776 B
  unsigned short* wr = (unsigned short*)((char*)d_ws + 55115776);   //  1,179,648 B

  quant_w<<<dim3((COUT * KTOT) / 256), dim3(256), 0, stream>>>(w, wr);
  pad_nhwc<<<dim3(BATCH * HP, 4), dim3(256), 0, stream>>>(x, xp);

  (void)hipFuncSetAttribute((const void*)conv_gemm,
                            hipFuncAttributeMaxDynamicSharedMemorySize, 131072);
  conv_gemm<<<dim3(392), dim3(512), 131072, stream>>>(wr, xp, bias, out);
}

// Round 3
// 326.972 us; speedup vs baseline: 1.0483x; 1.0483x over previous
//
#include <hip/hip_runtime.h>

#define CIN   256
#define COUT  256
#define HH    56
#define WW    56
#define BATCH 32
#define KTOT  2304           // CIN * 9, ordered (kh,kw,ci)
#define HP    58
#define WP    58
#define NPIX  (BATCH*HH*WW)  // 100352
#define HWSZ  (HH*WW)        // 3136
#define KT    36             // K-tiles of 64

typedef __bf16 bf16x8 __attribute__((ext_vector_type(8)));
typedef float  f32x4  __attribute__((ext_vector_type(4)));

#define AS1 __attribute__((address_space(1)))
#define AS3 __attribute__((address_space(3)))

__device__ __forceinline__ unsigned short f2bf(float f) {
  union { float f; unsigned int u; } v; v.f = f;
  unsigned int u = v.u;
  u += 0x7fffu + ((u >> 16) & 1u);   // round-to-nearest-even
  return (unsigned short)(u >> 16);
}

__device__ __forceinline__ void async16(const void* g, void* l) {
  __builtin_amdgcn_global_load_lds((const AS1 unsigned int*)g,
                                   (AS3 unsigned int*)l, 16, 0, 0);
}

// ---- kernel 1: ternary-quantize weights, reorder OIHW -> [co][kh][kw][ci] bf16
__global__ __launch_bounds__(256) void quant_w(const float* __restrict__ w,
                                               unsigned short* __restrict__ wr) {
  int tid = blockIdx.x * 256 + threadIdx.x;
  if (tid >= COUT * KTOT) return;
  int co  = tid / KTOT;
  int rem = tid - co * KTOT;
  int tap = rem >> 8;          // kh*3+kw
  int ci  = rem & 255;
  int kh  = tap / 3;
  int kw  = tap - kh * 3;
  float v = w[((co * CIN + ci) * 3 + kh) * 3 + kw];
  float q = (fabsf(v) > 0.05f) ? ((v > 0.f) ? 1.f : -1.f) : 0.f;
  wr[tid] = f2bf(q);           // -1/0/+1 exact in bf16
}

// ---- kernel 2: x NCHW fp32 -> zero-padded NHWC bf16  Xp[n][hp][wp][ci]
// LDS tile stride 60 (240 B): breaks the old stride-224B (= 0 mod 128) layout
// where all 8 ci-group lanes of a wp hit one bank (8-way conflict per read).
#define TSTR 60
__global__ __launch_bounds__(256) void pad_nhwc(const float* __restrict__ x,
                                                unsigned short* __restrict__ xp) {
  const int nhp = blockIdx.x;            // n*58 + hp
  const int n   = nhp / HP;
  const int hp  = nhp - n * HP;
  const int ci0 = blockIdx.y * 64;
  const int t   = threadIdx.x;
  const size_t obase = (size_t)nhp * (WP * 256);

  __shared__ __align__(16) float tile[64 * TSTR];
  const bool hborder = (hp == 0) || (hp == HP - 1);

  if (!hborder) {
    const int h = hp - 1;
    #pragma unroll
    for (int it = 0; it < 4; ++it) {
      int linear = it * 256 + t;
      if (linear < 896) {                // 64 ch x 14 float4
        int cil = linear / 14;
        int w4  = linear - cil * 14;
        *(float4*)&tile[cil * TSTR + w4 * 4] =
            *(const float4*)&x[(((size_t)(n * CIN + ci0 + cil)) * HH + h) * WW + w4 * 4];
      }
    }
  }
  __syncthreads();

  #pragma unroll
  for (int it = 0; it < 2; ++it) {               // 58*8 = 464 16B-chunks
    int linear = it * 256 + t;
    if (linear < 464) {
      int wp = linear >> 3;
      int g  = linear & 7;                       // ci group of 8
      unsigned int pk[4] = {0u, 0u, 0u, 0u};
      if (!hborder && wp != 0 && wp != WP - 1) {
        #pragma unroll
        for (int j = 0; j < 4; ++j) {
          unsigned int lo = f2bf(tile[(g * 8 + 2 * j) * TSTR + (wp - 1)]);
          unsigned int hi = f2bf(tile[(g * 8 + 2 * j + 1) * TSTR + (wp - 1)]);
          pk[j] = lo | (hi << 16);
        }
      }
      uint4 v; v.x = pk[0]; v.y = pk[1]; v.z = pk[2]; v.w = pk[3];
      *(uint4*)(xp + obase + (size_t)wp * 256 + ci0 + g * 8) = v;
    }
  }
}

// ---- kernel 3: implicit GEMM, 256x256 tile, BK=64, 8 waves (2Mx4N),
// 8-phase counted-vmcnt schedule (T3+T4) + chunk-XOR LDS swizzle (T2) +
// setprio (T5) + bijective XCD swizzle (T1).
//
// LDS (128 KiB dynamic):
//   A[buf][khalf][256 co][32 k]  regions of 16 KB at ((b*2+kh)*16384)
//   B[buf][khalf][256 px][32 k]  at 65536 + ((b*2+kh)*16384)
//
// T2 swizzle (CORRECTED): 16B-chunk c_phys = c_log ^ ((row>>1)&3).
// Derivation: row = 64 B so granule g = ((row&1)<<2)|chunk; only row bit 0
// reaches the bank bits. XOR by (row>>1)&3 makes rows of equal parity cycle
// all 4 chunks -> every 16-lane group spreads over all 8 granules x2 lanes
// (2-way = free, m136). The old row&3 XOR left a 4-way conflict (r2 counters).
// Staging keeps LDS linear and pre-swizzles the GLOBAL source (rule #21);
// ds_read applies the same XOR. Both sweeps (row, row+128) share the XOR
// since (row>>1)&3 depends on row bits 1..2 only and 128 = 0 mod 8.
//
// Pipeline (per tile kk, buffer b=kk&1; phases p1..p4 = (kh,mh)):
//   p1 issue A_kh1(kk+1)->b^1        | p2 issue B_kh1(kk+1)->b^1, vmcnt(8)
//   p3 issue A_kh0(kk+2)->b          | p4 issue B_kh0(kk+2)->b,   vmcnt(8)
// Waits sit BEFORE the trailing barrier => cross-wave safe; every overwrite
// issue is >=1 barrier after the region's last read. Never vmcnt(0) until the
// peeled final tile (vmcnt 4 then 0).

__device__ __forceinline__ int xko_of(int kk) {
  int tap = kk >> 2;               // 0..8
  int k3  = tap / 3;
  int w3  = tap - k3 * 3;
  return (k3 * WP + w3) * 256 + ((kk & 3) << 6);
}

#define NOWAIT (void)0
#define VM8 asm volatile("s_waitcnt vmcnt(8)" ::: "memory")
#define VM4 asm volatile("s_waitcnt vmcnt(4)" ::: "memory")
#define VM0 asm volatile("s_waitcnt vmcnt(0)" ::: "memory")

#define STAGE_A(b_, kh_, kkq_) do {                                           \
  const size_t ko_ = (size_t)(kkq_) * 64 + (kh_) * 32;                        \
  char* d_ = smem + (((b_) * 2 + (kh_)) * 16384) + t * 16;                    \
  async16(Wr + aOff0 + ko_, d_);                                              \
  async16(Wr + aOff1 + ko_, d_ + 8192);                                       \
} while (0)

#define STAGE_B(b_, kh_, xko_) do {                                           \
  const size_t ko_ = (size_t)(xko_) + (kh_) * 32;                             \
  char* d_ = smem + 65536 + (((b_) * 2 + (kh_)) * 16384) + t * 16;            \
  async16(Xp + bOff0 + ko_, d_);                                              \
  async16(Xp + bOff1 + ko_, d_ + 8192);                                       \
} while (0)

#define PHASE(b_, kh_, mh_, WAITE, ...) do {                                  \
  const int abase_ = ((b_) * 2 + (kh_)) * 16384;                              \
  const int bbase_ = 65536 + ((b_) * 2 + (kh_)) * 16384;                      \
  bf16x8 af_[4];                                                              \
  _Pragma("unroll")                                                           \
  for (int mt = 0; mt < 4; ++mt)                                              \
    af_[mt] = *(const bf16x8*)(smem + abase_ + rdA + (mh_) * 4096 + mt * 1024);\
  if ((mh_) == 0) {                                                           \
    _Pragma("unroll")                                                         \
    for (int nt = 0; nt < 4; ++nt)                                            \
      bfr[nt] = *(const bf16x8*)(smem + bbase_ + rdB + nt * 1024);            \
  }                                                                           \
  __VA_ARGS__;                                                                \
  __builtin_amdgcn_s_barrier();                                               \
  asm volatile("s_waitcnt lgkmcnt(0)" ::: "memory");                          \
  __builtin_amdgcn_sched_barrier(0);                                          \
  __builtin_amdgcn_s_setprio(1);                                              \
  _Pragma("unroll")                                                           \
  for (int mt = 0; mt < 4; ++mt)                                              \
    _Pragma("unroll")                                                         \
    for (int nt = 0; nt < 4; ++nt)                                            \
      acc[(mh_) * 4 + mt][nt] = __builtin_amdgcn_mfma_f32_16x16x32_bf16(      \
          af_[mt], bfr[nt], acc[(mh_) * 4 + mt][nt], 0, 0, 0);                \
  __builtin_amdgcn_s_setprio(0);                                              \
  WAITE;                                                                      \
  __builtin_amdgcn_s_barrier();                                               \
} while (0)

#define TILE_FULL(b_, kk_) do {                                               \
  const int kkn1_ = (kk_) + 1, kkn2_ = (kk_) + 2;                             \
  const int xko1_ = xko_of(kkn1_), xko2_ = xko_of(kkn2_);                     \
  PHASE(b_, 0, 0, NOWAIT, STAGE_A((b_) ^ 1, 1, kkn1_));                       \
  PHASE(b_, 0, 1, VM8,    STAGE_B((b_) ^ 1, 1, xko1_));                       \
  PHASE(b_, 1, 0, NOWAIT, STAGE_A((b_), 0, kkn2_));                           \
  PHASE(b_, 1, 1, VM8,    STAGE_B((b_), 0, xko2_));                           \
} while (0)

__global__ __launch_bounds__(512, 2) void conv_gemm(
    const unsigned short* __restrict__ Wr,
    const unsigned short* __restrict__ Xp,
    const float* __restrict__ bias,
    float* __restrict__ out) {
  extern __shared__ char smem[];   // 131072 B

  const int t    = threadIdx.x;
  const int lane = t & 63;
  const int wv   = t >> 6;        // 0..7
  const int wm   = wv >> 2;       // 0..1  (co half)
  const int wn   = wv & 3;        // 0..3  (pixel quarter)
  const int l15  = lane & 15;
  const int quad = lane >> 4;

  // T1: bijective XCD swizzle over 392 = 8 * 49 blocks
  const int bid = blockIdx.x;
  const int pb  = (bid & 7) * 49 + (bid >> 3);
  const int p0  = pb * 256;

  // staging invariants: thread t stages row srow (+128 for sweep 1),
  // physical 16B-chunk t&3, logical chunk schk = (t&3) ^ ((srow>>1)&3)  [T2]
  const int srow = t >> 2;                       // 0..127
  const int schk = (t & 3) ^ ((srow >> 1) & 3);
  const size_t aOff0 = (size_t)srow * KTOT + schk * 8;
  const size_t aOff1 = aOff0 + (size_t)128 * KTOT;

  const int pA = p0 + srow;
  const int pB = pA + 128;
  const int nA = pA / HWSZ;  const int hwA = pA - nA * HWSZ;
  const int hA = hwA / WW;   const int wA  = hwA - hA * WW;
  const int nB = pB / HWSZ;  const int hwB = pB - nB * HWSZ;
  const int hB = hwB / WW;   const int wB  = hwB - hB * WW;
  const size_t bOff0 = ((size_t)((nA * HP + hA) * WP + wA)) * 256 + schk * 8;
  const size_t bOff1 = ((size_t)((nB * HP + hB) * WP + wB)) * 256 + schk * 8;

  // fragment-read invariants (T2 read-side XOR: chunk = quad ^ ((row>>1)&3);
  // row = X*16 + l15 with X*16 = 0 mod 8, so (row>>1)&3 = (l15>>1)&3)
  const int rchk = ((quad ^ ((l15 >> 1) & 3)) * 16);
  const int rdA  = (wm * 128 + l15) * 64 + rchk;   // + mh*4096 + mt*1024
  const int rdB  = (wn * 64 + l15) * 64 + rchk;    // + nt*1024

  f32x4 acc[8][4];
  #pragma unroll
  for (int i = 0; i < 8; ++i)
    #pragma unroll
    for (int j = 0; j < 4; ++j)
      acc[i][j] = (f32x4){0.f, 0.f, 0.f, 0.f};
  bf16x8 bfr[4];

  // ---- prologue: issue (oldest->newest) A0(0) B0(0) A1(0) B1(0) A0(1) B0(1)
  STAGE_A(0, 0, 0);
  STAGE_B(0, 0, xko_of(0));
  STAGE_A(0, 1, 0);
  STAGE_B(0, 1, xko_of(0));
  STAGE_A(1, 0, 1);
  STAGE_B(1, 0, xko_of(1));
  VM8;                               // kh0(0) regions landed (8 still in flight)
  __builtin_amdgcn_s_barrier();

  // ---- main: tiles 0..33, uniform schedule
  #pragma unroll 1
  for (int kk = 0; kk < 34; kk += 2) {
    TILE_FULL(0, kk);
    TILE_FULL(1, kk + 1);
  }
  // ---- tile 34 (b=0): only kh1(35) issues remain; drain tapers 8 -> 4
  {
    const int xko35 = xko_of(35);
    PHASE(0, 0, 0, NOWAIT, STAGE_A(1, 1, 35));
    PHASE(0, 0, 1, VM8,    STAGE_B(1, 1, xko35));
    PHASE(0, 1, 0, NOWAIT, NOWAIT);
    PHASE(0, 1, 1, VM4,    NOWAIT);
  }
  // ---- tile 35 (b=1): final drain 0
  {
    PHASE(1, 0, 0, NOWAIT, NOWAIT);
    PHASE(1, 0, 1, VM0,    NOWAIT);
    PHASE(1, 1, 0, NOWAIT, NOWAIT);
    PHASE(1, 1, 1, NOWAIT, NOWAIT);
  }

  // ---- epilogue: C/D layout col = lane&15 (pixel), row = quad*4+reg (co)
  float bv[8][4];
  #pragma unroll
  for (int m = 0; m < 8; ++m)
    #pragma unroll
    for (int r = 0; r < 4; ++r)
      bv[m][r] = bias[wm * 128 + m * 16 + quad * 4 + r];

  #pragma unroll
  for (int nt = 0; nt < 4; ++nt) {
    const int p  = p0 + wn * 64 + nt * 16 + l15;
    const int np = p / HWSZ;
    const int hw = p - np * HWSZ;
    const size_t obase = (size_t)np * (COUT * HWSZ) + hw;
    #pragma unroll
    for (int m = 0; m < 8; ++m) {
      const int co = wm * 128 + m * 16 + quad * 4;
      #pragma unroll
      for (int r = 0; r < 4; ++r)
        out[obase + (size_t)(co + r) * HWSZ] = acc[m][nt][r] + bv[m][r];
    }
  }
}

extern "C" void kernel_launch(void* const* d_in, const int* in_sizes, int n_in,
                              void* d_out, int out_size, void* d_ws, size_t ws_size,
                              hipStream_t stream) {
  const float* x    = (const float*)d_in[0];
  const float* w    = (const float*)d_in[1];
  const float* bias = (const float*)d_in[2];
  float* out        = (float*)d_out;

  // workspace layout: Xp (padded NHWC bf16) then Wr (reordered ternary bf16)
  unsigned short* xp = (unsigned short*)d_ws;                       // 55,115,776 B
  unsigned short* wr = (unsigned short*)((char*)d_ws + 55115776);   //  1,179,648 B

  quant_w<<<dim3((COUT * KTOT) / 256), dim3(256), 0, stream>>>(w, wr);
  pad_nhwc<<<dim3(BATCH * HP, 4), dim3(256), 0, stream>>>(x, xp);

  (void)hipFuncSetAttribute((const void*)conv_gemm,
                            hipFuncAttributeMaxDynamicSharedMemorySize, 131072);
  conv_gemm<<<dim3(392), dim3(512), 131072, stream>>>(wr, xp, bias, out);
}